// Round 3
// baseline (247.675 us; speedup 1.0000x reference)
//
#include <hip/hip_runtime.h>
#include <hip/hip_bf16.h>

#define T_TOK 2048
#define DDIM  1024
#define IDIM  1024
#define NEXP  8
#define TOPK  2
#define MAXROWS (T_TOK * TOPK)

#define BM 128
#define BN 64
#define BK 64
#define LDT 72   // padded pitch in bf16 elems: 144 B = 36 banks -> 8-row collision period, reads 2-way (free)

typedef __attribute__((ext_vector_type(8))) short          s16x8;
typedef __attribute__((ext_vector_type(8))) unsigned short u16x8;
typedef __attribute__((ext_vector_type(4))) float          f32x4;

__device__ __forceinline__ unsigned short f2bf(float f) {
    unsigned int u = __builtin_bit_cast(unsigned int, f);
    unsigned int r = 0x7fffu + ((u >> 16) & 1u);
    return (unsigned short)((u + r) >> 16);
}

// ---------------- routing: build per-expert compact token lists ----------------
__global__ void route_kernel(const int* __restrict__ indices,
                             const float* __restrict__ weights,
                             const void* __restrict__ mask,
                             int* __restrict__ counts, int* __restrict__ offsets,
                             int* __restrict__ tok, float* __restrict__ wslot) {
    __shared__ int cnt[NEXP], offs[NEXP], cur[NEXP];
    __shared__ int is_u8;
    const int tid = threadIdx.x;
    const unsigned char* m8  = (const unsigned char*)mask;
    const int*           m32 = (const int*)mask;
    if (tid < NEXP) cnt[tid] = 0;
    if (tid == 0) is_u8 = 0;
    __syncthreads();
    int found = 0;
    for (int i = tid; i < T_TOK; i += blockDim.x)
        if ((i & 3) != 0 && m8[i] != 0) found = 1;
    if (found) atomicOr(&is_u8, 1);
    __syncthreads();
    const int u8mode = is_u8;
    for (int idx = tid; idx < MAXROWS; idx += blockDim.x) {
        int t = idx >> 1;  // K = 2
        int active = u8mode ? (m8[t] != 0) : (m32[t] != 0);
        if (active) atomicAdd(&cnt[indices[idx]], 1);
    }
    __syncthreads();
    if (tid == 0) {
        int run = 0;
        for (int e = 0; e < NEXP; ++e) { offs[e] = run; run += cnt[e]; }
    }
    __syncthreads();
    if (tid < NEXP) { counts[tid] = cnt[tid]; offsets[tid] = offs[tid]; cur[tid] = offs[tid]; }
    __syncthreads();
    for (int idx = tid; idx < MAXROWS; idx += blockDim.x) {
        int t = idx >> 1;
        int active = u8mode ? (m8[t] != 0) : (m32[t] != 0);
        if (active) {
            int e = indices[idx];
            int p = atomicAdd(&cur[e], 1);
            tok[p]   = t;
            wslot[p] = weights[idx];
        }
    }
}

// ---------------- x: f32 -> bf16 once ----------------
__global__ __launch_bounds__(256) void cvt_x_kernel(const float* __restrict__ x,
                                                    unsigned short* __restrict__ xb) {
    int i = (blockIdx.x * 256 + threadIdx.x) * 8;
    float4 a = *reinterpret_cast<const float4*>(x + i);
    float4 b = *reinterpret_cast<const float4*>(x + i + 4);
    u16x8 v;
    v[0] = f2bf(a.x); v[1] = f2bf(a.y); v[2] = f2bf(a.z); v[3] = f2bf(a.w);
    v[4] = f2bf(b.x); v[5] = f2bf(b.y); v[6] = f2bf(b.z); v[7] = f2bf(b.w);
    *reinterpret_cast<u16x8*>(xb + i) = v;
}

// ---------------- GEMM1: H = silu(X G^T) * (X U^T), per expert, 2-phase pipelined ----------------
__global__ __launch_bounds__(256) void gemm1_kernel(
    const unsigned short* __restrict__ xb,
    const float* __restrict__ gate, const float* __restrict__ up,
    const int* __restrict__ counts, const int* __restrict__ offsets,
    const int* __restrict__ tok, unsigned short* __restrict__ hb) {
    const int e     = blockIdx.z;
    const int n_e   = counts[e];
    const int tileM = blockIdx.y;
    if (tileM * BM >= n_e) return;
    const int off = offsets[e];
    const int n0  = blockIdx.x * BN;

    __shared__ unsigned short lA[BM * LDT];  // 18 KiB
    __shared__ unsigned short lG[BN * LDT];  //  9 KiB
    __shared__ unsigned short lU[BN * LDT];  //  9 KiB

    const int tid  = threadIdx.x;
    const int lane = tid & 63;
    const int wid  = tid >> 6;
    const int wm   = wid >> 1, wn = wid & 1;

    // A staging: thread -> (row = tid>>1, 32-elem half)
    const int ar = tid >> 1, ah = tid & 1;
    const int rowIdx = tileM * BM + ar;
    const int tIdx = (rowIdx < n_e) ? tok[off + rowIdx] : tok[off];
    const unsigned short* aSrc = xb + (size_t)tIdx * DDIM + ah * 32;
    unsigned short* aDst = &lA[ar * LDT + ah * 32];
    // B staging: thread -> (row = tid>>2, 16-f32 quarter)
    const int br = tid >> 2, bq = tid & 3;
    const float* gSrc = gate + ((size_t)e * IDIM + n0 + br) * DDIM + bq * 16;
    const float* uSrc = up   + ((size_t)e * IDIM + n0 + br) * DDIM + bq * 16;
    unsigned short* gDst = &lG[br * LDT + bq * 16];
    unsigned short* uDst = &lU[br * LDT + bq * 16];

    f32x4 accg[4][2] = {};
    f32x4 accu[4][2] = {};

    const int fr  = lane & 15;
    const int fkb = (lane >> 4) * 8;

    uint4  avr[4];
    float4 gvr[4], uvr[4];

    auto LOAD = [&](int k0) {
        const uint4*  ap = reinterpret_cast<const uint4*>(aSrc + k0);
        const float4* gp = reinterpret_cast<const float4*>(gSrc + k0);
        const float4* up_ = reinterpret_cast<const float4*>(uSrc + k0);
#pragma unroll
        for (int j = 0; j < 4; ++j) avr[j] = ap[j];
#pragma unroll
        for (int j = 0; j < 4; ++j) gvr[j] = gp[j];
#pragma unroll
        for (int j = 0; j < 4; ++j) uvr[j] = up_[j];
    };

    auto STORE = [&]() {
#pragma unroll
        for (int j = 0; j < 4; ++j)
            *reinterpret_cast<uint4*>(aDst + j * 8) = avr[j];
#pragma unroll
        for (int h = 0; h < 2; ++h) {
            u16x8 g, u;
#pragma unroll
            for (int j = 0; j < 4; ++j) {
                g[j]     = f2bf(gvr[2 * h][j == 0 ? 0 : j]);
                u[j]     = f2bf(uvr[2 * h][j]);
            }
            g[0] = f2bf(gvr[2 * h].x); g[1] = f2bf(gvr[2 * h].y);
            g[2] = f2bf(gvr[2 * h].z); g[3] = f2bf(gvr[2 * h].w);
            g[4] = f2bf(gvr[2 * h + 1].x); g[5] = f2bf(gvr[2 * h + 1].y);
            g[6] = f2bf(gvr[2 * h + 1].z); g[7] = f2bf(gvr[2 * h + 1].w);
            u[0] = f2bf(uvr[2 * h].x); u[1] = f2bf(uvr[2 * h].y);
            u[2] = f2bf(uvr[2 * h].z); u[3] = f2bf(uvr[2 * h].w);
            u[4] = f2bf(uvr[2 * h + 1].x); u[5] = f2bf(uvr[2 * h + 1].y);
            u[6] = f2bf(uvr[2 * h + 1].z); u[7] = f2bf(uvr[2 * h + 1].w);
            *reinterpret_cast<u16x8*>(gDst + h * 8) = g;
            *reinterpret_cast<u16x8*>(uDst + h * 8) = u;
        }
    };

    auto COMPUTE = [&]() {
#pragma unroll
        for (int ks = 0; ks < 2; ++ks) {
            s16x8 af[4], bg[2], bu[2];
#pragma unroll
            for (int m = 0; m < 4; ++m)
                af[m] = *reinterpret_cast<const s16x8*>(&lA[(wm * 64 + m * 16 + fr) * LDT + ks * 32 + fkb]);
#pragma unroll
            for (int n = 0; n < 2; ++n) {
                bg[n] = *reinterpret_cast<const s16x8*>(&lG[(wn * 32 + n * 16 + fr) * LDT + ks * 32 + fkb]);
                bu[n] = *reinterpret_cast<const s16x8*>(&lU[(wn * 32 + n * 16 + fr) * LDT + ks * 32 + fkb]);
            }
#pragma unroll
            for (int m = 0; m < 4; ++m)
#pragma unroll
                for (int n = 0; n < 2; ++n) {
                    accg[m][n] = __builtin_amdgcn_mfma_f32_16x16x32_bf16(af[m], bg[n], accg[m][n], 0, 0, 0);
                    accu[m][n] = __builtin_amdgcn_mfma_f32_16x16x32_bf16(af[m], bu[n], accu[m][n], 0, 0, 0);
                }
        }
    };

    LOAD(0);
    STORE();
    __syncthreads();
    const int NT = DDIM / BK;  // 16
    for (int t = 0; t < NT - 1; ++t) {
        LOAD((t + 1) * BK);   // issue early: in flight during COMPUTE
        COMPUTE();
        __syncthreads();
        STORE();              // vmcnt wait lands here, latency already hidden
        __syncthreads();
    }
    COMPUTE();

    const int rbase = tileM * BM;
#pragma unroll
    for (int m = 0; m < 4; ++m)
#pragma unroll
        for (int n = 0; n < 2; ++n)
#pragma unroll
            for (int j = 0; j < 4; ++j) {
                int rl = wm * 64 + m * 16 + (lane >> 4) * 4 + j;
                if (rbase + rl < n_e) {
                    int col = wn * 32 + n * 16 + fr;
                    float g = accg[m][n][j];
                    float u = accu[m][n][j];
                    float h = (g / (1.0f + __expf(-g))) * u;
                    hb[(size_t)(off + rbase + rl) * IDIM + n0 + col] = f2bf(h);
                }
            }
}

// ---------------- GEMM2: Y_rows = H D^T, weighted scatter-add, 2-phase pipelined ----------------
__global__ __launch_bounds__(256) void gemm2_kernel(
    const unsigned short* __restrict__ hb, const float* __restrict__ down,
    const int* __restrict__ counts, const int* __restrict__ offsets,
    const int* __restrict__ tok, const float* __restrict__ wslot,
    float* __restrict__ y) {
    const int e     = blockIdx.z;
    const int n_e   = counts[e];
    const int tileM = blockIdx.y;
    if (tileM * BM >= n_e) return;
    const int off = offsets[e];
    const int n0  = blockIdx.x * BN;

    __shared__ unsigned short lA[BM * LDT];
    __shared__ unsigned short lB[BN * LDT];

    const int tid  = threadIdx.x;
    const int lane = tid & 63;
    const int wid  = tid >> 6;
    const int wm   = wid >> 1, wn = wid & 1;

    const int ar = tid >> 1, ah = tid & 1;
    const int rowIdx = tileM * BM + ar;
    const int hrow = (rowIdx < n_e) ? (off + rowIdx) : off;
    const unsigned short* aSrc = hb + (size_t)hrow * IDIM + ah * 32;
    unsigned short* aDst = &lA[ar * LDT + ah * 32];
    const int br = tid >> 2, bq = tid & 3;
    const float* bSrc = down + ((size_t)e * DDIM + n0 + br) * IDIM + bq * 16;
    unsigned short* bDst = &lB[br * LDT + bq * 16];

    f32x4 acc[4][2] = {};

    const int fr  = lane & 15;
    const int fkb = (lane >> 4) * 8;

    uint4  avr[4];
    float4 bvr[4];

    auto LOAD = [&](int k0) {
        const uint4*  ap = reinterpret_cast<const uint4*>(aSrc + k0);
        const float4* bp = reinterpret_cast<const float4*>(bSrc + k0);
#pragma unroll
        for (int j = 0; j < 4; ++j) avr[j] = ap[j];
#pragma unroll
        for (int j = 0; j < 4; ++j) bvr[j] = bp[j];
    };

    auto STORE = [&]() {
#pragma unroll
        for (int j = 0; j < 4; ++j)
            *reinterpret_cast<uint4*>(aDst + j * 8) = avr[j];
#pragma unroll
        for (int h = 0; h < 2; ++h) {
            u16x8 b;
            b[0] = f2bf(bvr[2 * h].x); b[1] = f2bf(bvr[2 * h].y);
            b[2] = f2bf(bvr[2 * h].z); b[3] = f2bf(bvr[2 * h].w);
            b[4] = f2bf(bvr[2 * h + 1].x); b[5] = f2bf(bvr[2 * h + 1].y);
            b[6] = f2bf(bvr[2 * h + 1].z); b[7] = f2bf(bvr[2 * h + 1].w);
            *reinterpret_cast<u16x8*>(bDst + h * 8) = b;
        }
    };

    auto COMPUTE = [&]() {
#pragma unroll
        for (int ks = 0; ks < 2; ++ks) {
            s16x8 af[4], bf[2];
#pragma unroll
            for (int m = 0; m < 4; ++m)
                af[m] = *reinterpret_cast<const s16x8*>(&lA[(wm * 64 + m * 16 + fr) * LDT + ks * 32 + fkb]);
#pragma unroll
            for (int n = 0; n < 2; ++n)
                bf[n] = *reinterpret_cast<const s16x8*>(&lB[(wn * 32 + n * 16 + fr) * LDT + ks * 32 + fkb]);
#pragma unroll
            for (int m = 0; m < 4; ++m)
#pragma unroll
                for (int n = 0; n < 2; ++n)
                    acc[m][n] = __builtin_amdgcn_mfma_f32_16x16x32_bf16(af[m], bf[n], acc[m][n], 0, 0, 0);
        }
    };

    LOAD(0);
    STORE();
    __syncthreads();
    const int NT = IDIM / BK;
    for (int t = 0; t < NT - 1; ++t) {
        LOAD((t + 1) * BK);
        COMPUTE();
        __syncthreads();
        STORE();
        __syncthreads();
    }
    COMPUTE();

    const int rbase = tileM * BM;
#pragma unroll
    for (int m = 0; m < 4; ++m)
#pragma unroll
        for (int n = 0; n < 2; ++n)
#pragma unroll
            for (int j = 0; j < 4; ++j) {
                int rl = wm * 64 + m * 16 + (lane >> 4) * 4 + j;
                if (rbase + rl < n_e) {
                    int col = wn * 32 + n * 16 + fr;
                    int row = off + rbase + rl;
                    float v = acc[m][n][j] * wslot[row];
                    atomicAdd(&y[(size_t)tok[row] * DDIM + n0 + col], v);
                }
            }
}

extern "C" void kernel_launch(void* const* d_in, const int* in_sizes, int n_in,
                              void* d_out, int out_size, void* d_ws, size_t ws_size,
                              hipStream_t stream) {
    const float* x       = (const float*)d_in[0];
    const void*  mask    = d_in[1];
    const float* weights = (const float*)d_in[2];
    const int*   indices = (const int*)d_in[3];
    const float* gate    = (const float*)d_in[4];
    const float* up      = (const float*)d_in[5];
    const float* down    = (const float*)d_in[6];
    float*       y       = (float*)d_out;

    char* ws = (char*)d_ws;
    int*            counts  = (int*)ws;
    int*            offsets = (int*)(ws + 32);
    int*            tok     = (int*)(ws + 256);
    float*          wslot   = (float*)(ws + 256 + MAXROWS * 4);
    unsigned short* xb      = (unsigned short*)(ws + 65536);
    unsigned short* hb      = (unsigned short*)(ws + 65536 + (size_t)T_TOK * DDIM * 2);

    hipMemsetAsync(d_out, 0, (size_t)out_size * sizeof(float), stream);
    route_kernel<<<1, 256, 0, stream>>>(indices, weights, mask, counts, offsets, tok, wslot);
    cvt_x_kernel<<<(T_TOK * DDIM / 8) / 256, 256, 0, stream>>>(x, xb);

    dim3 g1(IDIM / BN, MAXROWS / BM, NEXP);
    gemm1_kernel<<<g1, 256, 0, stream>>>(xb, gate, up, counts, offsets, tok, hb);
    dim3 g2(DDIM / BN, MAXROWS / BM, NEXP);
    gemm2_kernel<<<g2, 256, 0, stream>>>(hb, down, counts, offsets, tok, wslot, y);
}

// Round 4
// 129.818 us; speedup vs baseline: 1.9079x; 1.9079x over previous
//
#include <hip/hip_runtime.h>
#include <hip/hip_bf16.h>

#define T_TOK 2048
#define DDIM  1024
#define IDIM  1024
#define NEXP  8
#define TOPK  2
#define MAXROWS (T_TOK * TOPK)

#define BM 64
#define BN 64
#define BK 32
#define LDT 40              // padded pitch (80 B): bank period 8 rows -> 2-way (free, m136)
#define BUFSZ (64 * LDT)    // elems per LDS tile buffer

typedef __attribute__((ext_vector_type(8))) short          s16x8;
typedef __attribute__((ext_vector_type(8))) unsigned short u16x8;
typedef __attribute__((ext_vector_type(4))) float          f32x4;

__device__ __forceinline__ unsigned short f2bf(float f) {
    unsigned int u = __builtin_bit_cast(unsigned int, f);
    unsigned int r = 0x7fffu + ((u >> 16) & 1u);
    return (unsigned short)((u + r) >> 16);
}

__device__ __forceinline__ u16x8 pack8(const float4& a, const float4& b) {
    u16x8 v;
    v[0] = f2bf(a.x); v[1] = f2bf(a.y); v[2] = f2bf(a.z); v[3] = f2bf(a.w);
    v[4] = f2bf(b.x); v[5] = f2bf(b.y); v[6] = f2bf(b.z); v[7] = f2bf(b.w);
    return v;
}

// ---------------- routing: build per-expert compact token lists ----------------
__global__ void route_kernel(const int* __restrict__ indices,
                             const float* __restrict__ weights,
                             const void* __restrict__ mask,
                             int* __restrict__ counts, int* __restrict__ offsets,
                             int* __restrict__ tok, float* __restrict__ wslot) {
    __shared__ int cnt[NEXP], offs[NEXP], cur[NEXP];
    __shared__ int is_u8;
    const int tid = threadIdx.x;
    const unsigned char* m8  = (const unsigned char*)mask;
    const int*           m32 = (const int*)mask;
    if (tid < NEXP) cnt[tid] = 0;
    if (tid == 0) is_u8 = 0;
    __syncthreads();
    int found = 0;
    for (int i = tid; i < T_TOK; i += blockDim.x)
        if ((i & 3) != 0 && m8[i] != 0) found = 1;
    if (found) atomicOr(&is_u8, 1);
    __syncthreads();
    const int u8mode = is_u8;
    for (int idx = tid; idx < MAXROWS; idx += blockDim.x) {
        int t = idx >> 1;  // K = 2
        int active = u8mode ? (m8[t] != 0) : (m32[t] != 0);
        if (active) atomicAdd(&cnt[indices[idx]], 1);
    }
    __syncthreads();
    if (tid == 0) {
        int run = 0;
        for (int e = 0; e < NEXP; ++e) { offs[e] = run; run += cnt[e]; }
    }
    __syncthreads();
    if (tid < NEXP) { counts[tid] = cnt[tid]; offsets[tid] = offs[tid]; cur[tid] = offs[tid]; }
    __syncthreads();
    for (int idx = tid; idx < MAXROWS; idx += blockDim.x) {
        int t = idx >> 1;
        int active = u8mode ? (m8[t] != 0) : (m32[t] != 0);
        if (active) {
            int e = indices[idx];
            int p = atomicAdd(&cur[e], 1);
            tok[p]   = t;
            wslot[p] = weights[idx];
        }
    }
}

// ---------------- x: f32 -> bf16 once ----------------
__global__ __launch_bounds__(256) void cvt_x_kernel(const float* __restrict__ x,
                                                    unsigned short* __restrict__ xb) {
    int i = (blockIdx.x * 256 + threadIdx.x) * 8;
    float4 a = *reinterpret_cast<const float4*>(x + i);
    float4 b = *reinterpret_cast<const float4*>(x + i + 4);
    *reinterpret_cast<u16x8*>(xb + i) = pack8(a, b);
}

// ---------------- GEMM1: H = silu(X G^T) * (X U^T), dbuf 1-barrier pipeline ----------------
__global__ __launch_bounds__(256) void gemm1_kernel(
    const unsigned short* __restrict__ xb,
    const float* __restrict__ gate, const float* __restrict__ up,
    const int* __restrict__ counts, const int* __restrict__ offsets,
    const int* __restrict__ tok, unsigned short* __restrict__ hb) {
    const int e     = blockIdx.z;
    const int n_e   = counts[e];
    const int tileM = blockIdx.y;
    if (tileM * BM >= n_e) return;
    const int off = offsets[e];
    const int n0  = blockIdx.x * BN;

    __shared__ unsigned short lA[2 * BUFSZ];
    __shared__ unsigned short lG[2 * BUFSZ];
    __shared__ unsigned short lU[2 * BUFSZ];

    const int tid  = threadIdx.x;
    const int lane = tid & 63;
    const int wid  = tid >> 6;
    const int wm   = wid >> 1, wn = wid & 1;

    // staging: thread -> (row = tid>>2, 8-elem segment tid&3)
    const int sr = tid >> 2, sseg = tid & 3;
    const int rowIdx = tileM * BM + sr;
    const int tIdx = (rowIdx < n_e) ? tok[off + rowIdx] : tok[off];
    const unsigned short* aSrc = xb + (size_t)tIdx * DDIM + sseg * 8;
    const float* gSrc = gate + ((size_t)e * IDIM + n0 + sr) * DDIM + sseg * 8;
    const float* uSrc = up   + ((size_t)e * IDIM + n0 + sr) * DDIM + sseg * 8;
    const int dstOff = sr * LDT + sseg * 8;

    f32x4 accg[2][2] = {};
    f32x4 accu[2][2] = {};

    const int fr  = lane & 15;
    const int fkb = (lane >> 4) * 8;

    uint4  av;
    float4 gv0, gv1, uv0, uv1;

    auto LOAD = [&](int k0) {
        av  = *reinterpret_cast<const uint4*>(aSrc + k0);
        gv0 = *reinterpret_cast<const float4*>(gSrc + k0);
        gv1 = *reinterpret_cast<const float4*>(gSrc + k0 + 4);
        uv0 = *reinterpret_cast<const float4*>(uSrc + k0);
        uv1 = *reinterpret_cast<const float4*>(uSrc + k0 + 4);
    };

    auto STORE = [&](int b) {
        *reinterpret_cast<uint4*>(&lA[b * BUFSZ + dstOff]) = av;
        *reinterpret_cast<u16x8*>(&lG[b * BUFSZ + dstOff]) = pack8(gv0, gv1);
        *reinterpret_cast<u16x8*>(&lU[b * BUFSZ + dstOff]) = pack8(uv0, uv1);
    };

    auto COMPUTE = [&](int b) {
        const unsigned short* pA = &lA[b * BUFSZ];
        const unsigned short* pG = &lG[b * BUFSZ];
        const unsigned short* pU = &lU[b * BUFSZ];
        s16x8 a0  = *reinterpret_cast<const s16x8*>(pA + (wm * 32 + fr) * LDT + fkb);
        s16x8 a1  = *reinterpret_cast<const s16x8*>(pA + (wm * 32 + 16 + fr) * LDT + fkb);
        s16x8 bg0 = *reinterpret_cast<const s16x8*>(pG + (wn * 32 + fr) * LDT + fkb);
        s16x8 bg1 = *reinterpret_cast<const s16x8*>(pG + (wn * 32 + 16 + fr) * LDT + fkb);
        s16x8 bu0 = *reinterpret_cast<const s16x8*>(pU + (wn * 32 + fr) * LDT + fkb);
        s16x8 bu1 = *reinterpret_cast<const s16x8*>(pU + (wn * 32 + 16 + fr) * LDT + fkb);
        accg[0][0] = __builtin_amdgcn_mfma_f32_16x16x32_bf16(a0, bg0, accg[0][0], 0, 0, 0);
        accg[0][1] = __builtin_amdgcn_mfma_f32_16x16x32_bf16(a0, bg1, accg[0][1], 0, 0, 0);
        accg[1][0] = __builtin_amdgcn_mfma_f32_16x16x32_bf16(a1, bg0, accg[1][0], 0, 0, 0);
        accg[1][1] = __builtin_amdgcn_mfma_f32_16x16x32_bf16(a1, bg1, accg[1][1], 0, 0, 0);
        accu[0][0] = __builtin_amdgcn_mfma_f32_16x16x32_bf16(a0, bu0, accu[0][0], 0, 0, 0);
        accu[0][1] = __builtin_amdgcn_mfma_f32_16x16x32_bf16(a0, bu1, accu[0][1], 0, 0, 0);
        accu[1][0] = __builtin_amdgcn_mfma_f32_16x16x32_bf16(a1, bu0, accu[1][0], 0, 0, 0);
        accu[1][1] = __builtin_amdgcn_mfma_f32_16x16x32_bf16(a1, bu1, accu[1][1], 0, 0, 0);
    };

    LOAD(0);
    STORE(0);
    __syncthreads();
    const int NT = DDIM / BK;  // 32
    for (int t = 0; t < NT - 1; ++t) {
        LOAD((t + 1) * BK);    // in flight across COMPUTE (vmcnt waits at STORE)
        COMPUTE(t & 1);
        STORE((t + 1) & 1);    // opposite buffer: no pre-MFMA drain needed
        __syncthreads();       // single barrier per K-iter
    }
    COMPUTE((NT - 1) & 1);

    const int rbase = tileM * BM;
#pragma unroll
    for (int m = 0; m < 2; ++m)
#pragma unroll
        for (int n = 0; n < 2; ++n)
#pragma unroll
            for (int j = 0; j < 4; ++j) {
                int rl = wm * 32 + m * 16 + (lane >> 4) * 4 + j;
                if (rbase + rl < n_e) {
                    int col = wn * 32 + n * 16 + fr;
                    float g = accg[m][n][j];
                    float u = accu[m][n][j];
                    float h = (g / (1.0f + __expf(-g))) * u;
                    hb[(size_t)(off + rbase + rl) * IDIM + n0 + col] = f2bf(h);
                }
            }
}

// ---------------- GEMM2: Y_rows = H D^T, weighted scatter-add, dbuf pipeline ----------------
__global__ __launch_bounds__(256) void gemm2_kernel(
    const unsigned short* __restrict__ hb, const float* __restrict__ down,
    const int* __restrict__ counts, const int* __restrict__ offsets,
    const int* __restrict__ tok, const float* __restrict__ wslot,
    float* __restrict__ y) {
    const int e     = blockIdx.z;
    const int n_e   = counts[e];
    const int tileM = blockIdx.y;
    if (tileM * BM >= n_e) return;
    const int off = offsets[e];
    const int n0  = blockIdx.x * BN;

    __shared__ unsigned short lA[2 * BUFSZ];
    __shared__ unsigned short lB[2 * BUFSZ];

    const int tid  = threadIdx.x;
    const int lane = tid & 63;
    const int wid  = tid >> 6;
    const int wm   = wid >> 1, wn = wid & 1;

    const int sr = tid >> 2, sseg = tid & 3;
    const int rowIdx = tileM * BM + sr;
    const int hrow = (rowIdx < n_e) ? (off + rowIdx) : off;
    const unsigned short* aSrc = hb + (size_t)hrow * IDIM + sseg * 8;
    const float* bSrc = down + ((size_t)e * DDIM + n0 + sr) * IDIM + sseg * 8;
    const int dstOff = sr * LDT + sseg * 8;

    f32x4 acc[2][2] = {};

    const int fr  = lane & 15;
    const int fkb = (lane >> 4) * 8;

    uint4  av;
    float4 bv0, bv1;

    auto LOAD = [&](int k0) {
        av  = *reinterpret_cast<const uint4*>(aSrc + k0);
        bv0 = *reinterpret_cast<const float4*>(bSrc + k0);
        bv1 = *reinterpret_cast<const float4*>(bSrc + k0 + 4);
    };

    auto STORE = [&](int b) {
        *reinterpret_cast<uint4*>(&lA[b * BUFSZ + dstOff]) = av;
        *reinterpret_cast<u16x8*>(&lB[b * BUFSZ + dstOff]) = pack8(bv0, bv1);
    };

    auto COMPUTE = [&](int b) {
        const unsigned short* pA = &lA[b * BUFSZ];
        const unsigned short* pB = &lB[b * BUFSZ];
        s16x8 a0 = *reinterpret_cast<const s16x8*>(pA + (wm * 32 + fr) * LDT + fkb);
        s16x8 a1 = *reinterpret_cast<const s16x8*>(pA + (wm * 32 + 16 + fr) * LDT + fkb);
        s16x8 b0 = *reinterpret_cast<const s16x8*>(pB + (wn * 32 + fr) * LDT + fkb);
        s16x8 b1 = *reinterpret_cast<const s16x8*>(pB + (wn * 32 + 16 + fr) * LDT + fkb);
        acc[0][0] = __builtin_amdgcn_mfma_f32_16x16x32_bf16(a0, b0, acc[0][0], 0, 0, 0);
        acc[0][1] = __builtin_amdgcn_mfma_f32_16x16x32_bf16(a0, b1, acc[0][1], 0, 0, 0);
        acc[1][0] = __builtin_amdgcn_mfma_f32_16x16x32_bf16(a1, b0, acc[1][0], 0, 0, 0);
        acc[1][1] = __builtin_amdgcn_mfma_f32_16x16x32_bf16(a1, b1, acc[1][1], 0, 0, 0);
    };

    LOAD(0);
    STORE(0);
    __syncthreads();
    const int NT = IDIM / BK;
    for (int t = 0; t < NT - 1; ++t) {
        LOAD((t + 1) * BK);
        COMPUTE(t & 1);
        STORE((t + 1) & 1);
        __syncthreads();
    }
    COMPUTE((NT - 1) & 1);

    const int rbase = tileM * BM;
#pragma unroll
    for (int m = 0; m < 2; ++m)
#pragma unroll
        for (int n = 0; n < 2; ++n)
#pragma unroll
            for (int j = 0; j < 4; ++j) {
                int rl = wm * 32 + m * 16 + (lane >> 4) * 4 + j;
                if (rbase + rl < n_e) {
                    int col = wn * 32 + n * 16 + fr;
                    int row = off + rbase + rl;
                    float v = acc[m][n][j] * wslot[row];
                    atomicAdd(&y[(size_t)tok[row] * DDIM + n0 + col], v);
                }
            }
}

extern "C" void kernel_launch(void* const* d_in, const int* in_sizes, int n_in,
                              void* d_out, int out_size, void* d_ws, size_t ws_size,
                              hipStream_t stream) {
    const float* x       = (const float*)d_in[0];
    const void*  mask    = d_in[1];
    const float* weights = (const float*)d_in[2];
    const int*   indices = (const int*)d_in[3];
    const float* gate    = (const float*)d_in[4];
    const float* up      = (const float*)d_in[5];
    const float* down    = (const float*)d_in[6];
    float*       y       = (float*)d_out;

    char* ws = (char*)d_ws;
    int*            counts  = (int*)ws;
    int*            offsets = (int*)(ws + 32);
    int*            tok     = (int*)(ws + 256);
    float*          wslot   = (float*)(ws + 256 + MAXROWS * 4);
    unsigned short* xb      = (unsigned short*)(ws + 65536);
    unsigned short* hb      = (unsigned short*)(ws + 65536 + (size_t)T_TOK * DDIM * 2);

    hipMemsetAsync(d_out, 0, (size_t)out_size * sizeof(float), stream);
    route_kernel<<<1, 256, 0, stream>>>(indices, weights, mask, counts, offsets, tok, wslot);
    cvt_x_kernel<<<(T_TOK * DDIM / 8) / 256, 256, 0, stream>>>(x, xb);

    dim3 g1(IDIM / BN, MAXROWS / BM, NEXP);
    gemm1_kernel<<<g1, 256, 0, stream>>>(xb, gate, up, counts, offsets, tok, hb);
    dim3 g2(DDIM / BN, MAXROWS / BM, NEXP);
    gemm2_kernel<<<g2, 256, 0, stream>>>(hb, down, counts, offsets, tok, wslot, y);
}

// Round 5
// 127.159 us; speedup vs baseline: 1.9478x; 1.0209x over previous
//
#include <hip/hip_runtime.h>
#include <hip/hip_bf16.h>

#define T_TOK 2048
#define DDIM  1024
#define IDIM  1024
#define NEXP  8
#define TOPK  2
#define MAXROWS (T_TOK * TOPK)

#define BM 64
#define BN 64
#define BK 32
#define LDT 40              // padded pitch (80 B): read conflicts 2-way (free, m136)
#define BUFSZ (64 * LDT)    // elems per LDS tile buffer

typedef __attribute__((ext_vector_type(8))) short          s16x8;
typedef __attribute__((ext_vector_type(8))) unsigned short u16x8;
typedef __attribute__((ext_vector_type(4))) float          f32x4;

__device__ __forceinline__ unsigned short f2bf(float f) {
    return __builtin_bit_cast(unsigned short, __float2bfloat16(f));
}

__device__ __forceinline__ u16x8 pack8(const float4& a, const float4& b) {
    u16x8 v;
    v[0] = f2bf(a.x); v[1] = f2bf(a.y); v[2] = f2bf(a.z); v[3] = f2bf(a.w);
    v[4] = f2bf(b.x); v[5] = f2bf(b.y); v[6] = f2bf(b.z); v[7] = f2bf(b.w);
    return v;
}

// ---------------- routing: build per-expert compact token lists ----------------
__global__ void route_kernel(const int* __restrict__ indices,
                             const float* __restrict__ weights,
                             const void* __restrict__ mask,
                             int* __restrict__ counts, int* __restrict__ offsets,
                             int* __restrict__ tok, float* __restrict__ wslot) {
    __shared__ int cnt[NEXP], offs[NEXP], cur[NEXP];
    __shared__ int is_u8;
    const int tid = threadIdx.x;
    const unsigned char* m8  = (const unsigned char*)mask;
    const int*           m32 = (const int*)mask;
    if (tid < NEXP) cnt[tid] = 0;
    if (tid == 0) is_u8 = 0;
    __syncthreads();
    int found = 0;
    for (int i = tid; i < T_TOK; i += blockDim.x)
        if ((i & 3) != 0 && m8[i] != 0) found = 1;
    if (found) atomicOr(&is_u8, 1);
    __syncthreads();
    const int u8mode = is_u8;
    for (int idx = tid; idx < MAXROWS; idx += blockDim.x) {
        int t = idx >> 1;  // K = 2
        int active = u8mode ? (m8[t] != 0) : (m32[t] != 0);
        if (active) atomicAdd(&cnt[indices[idx]], 1);
    }
    __syncthreads();
    if (tid == 0) {
        int run = 0;
        for (int e = 0; e < NEXP; ++e) { offs[e] = run; run += cnt[e]; }
    }
    __syncthreads();
    if (tid < NEXP) { counts[tid] = cnt[tid]; offsets[tid] = offs[tid]; cur[tid] = offs[tid]; }
    __syncthreads();
    for (int idx = tid; idx < MAXROWS; idx += blockDim.x) {
        int t = idx >> 1;
        int active = u8mode ? (m8[t] != 0) : (m32[t] != 0);
        if (active) {
            int e = indices[idx];
            int p = atomicAdd(&cur[e], 1);
            tok[p]   = t;
            wslot[p] = weights[idx];
        }
    }
}

// ---------------- x: f32 -> bf16 once ----------------
__global__ __launch_bounds__(256) void cvt_x_kernel(const float* __restrict__ x,
                                                    unsigned short* __restrict__ xb) {
    int i = (blockIdx.x * 256 + threadIdx.x) * 8;
    float4 a = *reinterpret_cast<const float4*>(x + i);
    float4 b = *reinterpret_cast<const float4*>(x + i + 4);
    *reinterpret_cast<u16x8*>(xb + i) = pack8(a, b);
}

// ---------------- GEMM1: H = silu(X G^T) * (X U^T), 2-deep reg prefetch ----------------
__global__ __launch_bounds__(256) void gemm1_kernel(
    const unsigned short* __restrict__ xb,
    const float* __restrict__ gate, const float* __restrict__ up,
    const int* __restrict__ counts, const int* __restrict__ offsets,
    const int* __restrict__ tok, unsigned short* __restrict__ hb) {
    const int e     = blockIdx.z;
    const int n_e   = counts[e];
    const int tileM = blockIdx.y;
    if (tileM * BM >= n_e) return;
    const int off = offsets[e];
    const int n0  = blockIdx.x * BN;

    __shared__ unsigned short lA[2 * BUFSZ];
    __shared__ unsigned short lG[2 * BUFSZ];
    __shared__ unsigned short lU[2 * BUFSZ];

    const int tid  = threadIdx.x;
    const int lane = tid & 63;
    const int wid  = tid >> 6;
    const int wm   = wid >> 1, wn = wid & 1;

    const int sr = tid >> 2, sseg = tid & 3;
    const int rowIdx = tileM * BM + sr;
    const int tIdx = (rowIdx < n_e) ? tok[off + rowIdx] : tok[off];
    const unsigned short* aSrc = xb + (size_t)tIdx * DDIM + sseg * 8;
    const float* gSrc = gate + ((size_t)e * IDIM + n0 + sr) * DDIM + sseg * 8;
    const float* uSrc = up   + ((size_t)e * IDIM + n0 + sr) * DDIM + sseg * 8;
    const int dstOff = sr * LDT + sseg * 8;

    f32x4 accg[2][2] = {};
    f32x4 accu[2][2] = {};

    const int fr  = lane & 15;
    const int fkb = (lane >> 4) * 8;

    // two named register sets (static indexing — rule #20)
    uint4  av0, av1;
    float4 g0a, g0b, u0a, u0b;
    float4 g1a, g1b, u1a, u1b;

#define G1_LOAD(AV, GA, GB, UA, UB, K0)                                   \
    do {                                                                  \
        AV = *reinterpret_cast<const uint4*>(aSrc + (K0));                \
        GA = *reinterpret_cast<const float4*>(gSrc + (K0));               \
        GB = *reinterpret_cast<const float4*>(gSrc + (K0) + 4);           \
        UA = *reinterpret_cast<const float4*>(uSrc + (K0));               \
        UB = *reinterpret_cast<const float4*>(uSrc + (K0) + 4);           \
    } while (0)

#define G1_STORE(AV, GA, GB, UA, UB, B)                                   \
    do {                                                                  \
        *reinterpret_cast<uint4*>(&lA[(B) * BUFSZ + dstOff]) = AV;        \
        *reinterpret_cast<u16x8*>(&lG[(B) * BUFSZ + dstOff]) = pack8(GA, GB); \
        *reinterpret_cast<u16x8*>(&lU[(B) * BUFSZ + dstOff]) = pack8(UA, UB); \
    } while (0)

    auto COMPUTE = [&](int b) {
        const unsigned short* pA = &lA[b * BUFSZ];
        const unsigned short* pG = &lG[b * BUFSZ];
        const unsigned short* pU = &lU[b * BUFSZ];
        s16x8 a0  = *reinterpret_cast<const s16x8*>(pA + (wm * 32 + fr) * LDT + fkb);
        s16x8 a1  = *reinterpret_cast<const s16x8*>(pA + (wm * 32 + 16 + fr) * LDT + fkb);
        s16x8 bg0 = *reinterpret_cast<const s16x8*>(pG + (wn * 32 + fr) * LDT + fkb);
        s16x8 bg1 = *reinterpret_cast<const s16x8*>(pG + (wn * 32 + 16 + fr) * LDT + fkb);
        s16x8 bu0 = *reinterpret_cast<const s16x8*>(pU + (wn * 32 + fr) * LDT + fkb);
        s16x8 bu1 = *reinterpret_cast<const s16x8*>(pU + (wn * 32 + 16 + fr) * LDT + fkb);
        accg[0][0] = __builtin_amdgcn_mfma_f32_16x16x32_bf16(a0, bg0, accg[0][0], 0, 0, 0);
        accg[0][1] = __builtin_amdgcn_mfma_f32_16x16x32_bf16(a0, bg1, accg[0][1], 0, 0, 0);
        accg[1][0] = __builtin_amdgcn_mfma_f32_16x16x32_bf16(a1, bg0, accg[1][0], 0, 0, 0);
        accg[1][1] = __builtin_amdgcn_mfma_f32_16x16x32_bf16(a1, bg1, accg[1][1], 0, 0, 0);
        accu[0][0] = __builtin_amdgcn_mfma_f32_16x16x32_bf16(a0, bu0, accu[0][0], 0, 0, 0);
        accu[0][1] = __builtin_amdgcn_mfma_f32_16x16x32_bf16(a0, bu1, accu[0][1], 0, 0, 0);
        accu[1][0] = __builtin_amdgcn_mfma_f32_16x16x32_bf16(a1, bu0, accu[1][0], 0, 0, 0);
        accu[1][1] = __builtin_amdgcn_mfma_f32_16x16x32_bf16(a1, bu1, accu[1][1], 0, 0, 0);
    };

    const int NT = DDIM / BK;  // 32 (even)
    G1_LOAD(av0, g0a, g0b, u0a, u0b, 0);
    G1_STORE(av0, g0a, g0b, u0a, u0b, 0);
    G1_LOAD(av1, g1a, g1b, u1a, u1b, BK);
    __syncthreads();
    for (int t = 0; t + 3 < NT; t += 2) {
        G1_LOAD(av0, g0a, g0b, u0a, u0b, (t + 2) * BK);  // full-iter ahead of its STORE
        COMPUTE(0);
        G1_STORE(av1, g1a, g1b, u1a, u1b, 1);
        __syncthreads();
        G1_LOAD(av1, g1a, g1b, u1a, u1b, (t + 3) * BK);
        COMPUTE(1);
        G1_STORE(av0, g0a, g0b, u0a, u0b, 0);
        __syncthreads();
    }
    COMPUTE(0);                          // tile NT-2
    G1_STORE(av1, g1a, g1b, u1a, u1b, 1);
    __syncthreads();
    COMPUTE(1);                          // tile NT-1
#undef G1_LOAD
#undef G1_STORE

    const int rbase = tileM * BM;
#pragma unroll
    for (int m = 0; m < 2; ++m)
#pragma unroll
        for (int n = 0; n < 2; ++n)
#pragma unroll
            for (int j = 0; j < 4; ++j) {
                int rl = wm * 32 + m * 16 + (lane >> 4) * 4 + j;
                if (rbase + rl < n_e) {
                    int col = wn * 32 + n * 16 + fr;
                    float g = accg[m][n][j];
                    float u = accu[m][n][j];
                    float h = (g / (1.0f + __expf(-g))) * u;
                    hb[(size_t)(off + rbase + rl) * IDIM + n0 + col] = f2bf(h);
                }
            }
}

// ---------------- GEMM2: Y_rows = H D^T, weighted scatter-add, 2-deep prefetch ----------------
__global__ __launch_bounds__(256) void gemm2_kernel(
    const unsigned short* __restrict__ hb, const float* __restrict__ down,
    const int* __restrict__ counts, const int* __restrict__ offsets,
    const int* __restrict__ tok, const float* __restrict__ wslot,
    float* __restrict__ y) {
    const int e     = blockIdx.z;
    const int n_e   = counts[e];
    const int tileM = blockIdx.y;
    if (tileM * BM >= n_e) return;
    const int off = offsets[e];
    const int n0  = blockIdx.x * BN;

    __shared__ unsigned short lA[2 * BUFSZ];
    __shared__ unsigned short lB[2 * BUFSZ];

    const int tid  = threadIdx.x;
    const int lane = tid & 63;
    const int wid  = tid >> 6;
    const int wm   = wid >> 1, wn = wid & 1;

    const int sr = tid >> 2, sseg = tid & 3;
    const int rowIdx = tileM * BM + sr;
    const int hrow = (rowIdx < n_e) ? (off + rowIdx) : off;
    const unsigned short* aSrc = hb + (size_t)hrow * IDIM + sseg * 8;
    const float* bSrc = down + ((size_t)e * DDIM + n0 + sr) * IDIM + sseg * 8;
    const int dstOff = sr * LDT + sseg * 8;

    f32x4 acc[2][2] = {};

    const int fr  = lane & 15;
    const int fkb = (lane >> 4) * 8;

    uint4  av0, av1;
    float4 b0a, b0b, b1a, b1b;

#define G2_LOAD(AV, BA, BB, K0)                                           \
    do {                                                                  \
        AV = *reinterpret_cast<const uint4*>(aSrc + (K0));                \
        BA = *reinterpret_cast<const float4*>(bSrc + (K0));               \
        BB = *reinterpret_cast<const float4*>(bSrc + (K0) + 4);           \
    } while (0)

#define G2_STORE(AV, BA, BB, B)                                           \
    do {                                                                  \
        *reinterpret_cast<uint4*>(&lA[(B) * BUFSZ + dstOff]) = AV;        \
        *reinterpret_cast<u16x8*>(&lB[(B) * BUFSZ + dstOff]) = pack8(BA, BB); \
    } while (0)

    auto COMPUTE = [&](int b) {
        const unsigned short* pA = &lA[b * BUFSZ];
        const unsigned short* pB = &lB[b * BUFSZ];
        s16x8 a0 = *reinterpret_cast<const s16x8*>(pA + (wm * 32 + fr) * LDT + fkb);
        s16x8 a1 = *reinterpret_cast<const s16x8*>(pA + (wm * 32 + 16 + fr) * LDT + fkb);
        s16x8 b0 = *reinterpret_cast<const s16x8*>(pB + (wn * 32 + fr) * LDT + fkb);
        s16x8 b1 = *reinterpret_cast<const s16x8*>(pB + (wn * 32 + 16 + fr) * LDT + fkb);
        acc[0][0] = __builtin_amdgcn_mfma_f32_16x16x32_bf16(a0, b0, acc[0][0], 0, 0, 0);
        acc[0][1] = __builtin_amdgcn_mfma_f32_16x16x32_bf16(a0, b1, acc[0][1], 0, 0, 0);
        acc[1][0] = __builtin_amdgcn_mfma_f32_16x16x32_bf16(a1, b0, acc[1][0], 0, 0, 0);
        acc[1][1] = __builtin_amdgcn_mfma_f32_16x16x32_bf16(a1, b1, acc[1][1], 0, 0, 0);
    };

    const int NT = IDIM / BK;  // 32 (even)
    G2_LOAD(av0, b0a, b0b, 0);
    G2_STORE(av0, b0a, b0b, 0);
    G2_LOAD(av1, b1a, b1b, BK);
    __syncthreads();
    for (int t = 0; t + 3 < NT; t += 2) {
        G2_LOAD(av0, b0a, b0b, (t + 2) * BK);
        COMPUTE(0);
        G2_STORE(av1, b1a, b1b, 1);
        __syncthreads();
        G2_LOAD(av1, b1a, b1b, (t + 3) * BK);
        COMPUTE(1);
        G2_STORE(av0, b0a, b0b, 0);
        __syncthreads();
    }
    COMPUTE(0);
    G2_STORE(av1, b1a, b1b, 1);
    __syncthreads();
    COMPUTE(1);
#undef G2_LOAD
#undef G2_STORE

    const int rbase = tileM * BM;
#pragma unroll
    for (int m = 0; m < 2; ++m)
#pragma unroll
        for (int n = 0; n < 2; ++n)
#pragma unroll
            for (int j = 0; j < 4; ++j) {
                int rl = wm * 32 + m * 16 + (lane >> 4) * 4 + j;
                if (rbase + rl < n_e) {
                    int col = wn * 32 + n * 16 + fr;
                    int row = off + rbase + rl;
                    float v = acc[m][n][j] * wslot[row];
                    atomicAdd(&y[(size_t)tok[row] * DDIM + n0 + col], v);
                }
            }
}

extern "C" void kernel_launch(void* const* d_in, const int* in_sizes, int n_in,
                              void* d_out, int out_size, void* d_ws, size_t ws_size,
                              hipStream_t stream) {
    const float* x       = (const float*)d_in[0];
    const void*  mask    = d_in[1];
    const float* weights = (const float*)d_in[2];
    const int*   indices = (const int*)d_in[3];
    const float* gate    = (const float*)d_in[4];
    const float* up      = (const float*)d_in[5];
    const float* down    = (const float*)d_in[6];
    float*       y       = (float*)d_out;

    char* ws = (char*)d_ws;
    int*            counts  = (int*)ws;
    int*            offsets = (int*)(ws + 32);
    int*            tok     = (int*)(ws + 256);
    float*          wslot   = (float*)(ws + 256 + MAXROWS * 4);
    unsigned short* xb      = (unsigned short*)(ws + 65536);
    unsigned short* hb      = (unsigned short*)(ws + 65536 + (size_t)T_TOK * DDIM * 2);

    hipMemsetAsync(d_out, 0, (size_t)out_size * sizeof(float), stream);
    route_kernel<<<1, 256, 0, stream>>>(indices, weights, mask, counts, offsets, tok, wslot);
    cvt_x_kernel<<<(T_TOK * DDIM / 8) / 256, 256, 0, stream>>>(x, xb);

    dim3 g1(IDIM / BN, MAXROWS / BM, NEXP);
    gemm1_kernel<<<g1, 256, 0, stream>>>(xb, gate, up, counts, offsets, tok, hb);
    dim3 g2(DDIM / BN, MAXROWS / BM, NEXP);
    gemm2_kernel<<<g2, 256, 0, stream>>>(hb, down, counts, offsets, tok, wslot, y);
}